// Round 1
// baseline (3670.918 us; speedup 1.0000x reference)
//
#include <hip/hip_runtime.h>
#include <math.h>

// ---------------- problem constants ----------------
constexpr int B_    = 64;
constexpr int NPG_  = 2048;
constexpr int N_    = B_ * NPG_;        // 131072
constexpr int E_    = N_ * 16;          // 2097152
constexpr int NF_   = 128;
constexpr int EF_   = 32;
constexpr int TLD_  = 97;
constexpr int K_    = 30;
constexpr int C1_   = 16;
constexpr int C2_   = 32;
constexpr int KW2_  = 5;
constexpr int P2_   = 15;               // after maxpool(2,2) of K=30
constexpr int U_    = 11;               // conv2 output positions
constexpr int DENSE_= C2_ * U_;         // 352
constexpr int HID_  = 128;
constexpr int NCLS_ = 10;
constexpr int CATLD = 128;              // padded leading dim for cat[N][97]

#define FATOMIC(p, v) __hip_atomic_fetch_add((p), (v), __ATOMIC_RELAXED, __HIP_MEMORY_SCOPE_AGENT)

// ---------------- e2n: scatter edge features onto source nodes ----------------
__global__ __launch_bounds__(256) void k_e2n_scatter(const float4* __restrict__ ef4,
                                                     const int* __restrict__ erow,
                                                     float* __restrict__ e2n)
{
    int gid = blockIdx.x * 256 + threadIdx.x;      // E*8 threads
    int e = gid >> 3, j4 = gid & 7;
    float4 v = ef4[gid];
    int r = erow[e];
    float* dst = e2n + (long)r * EF_ + j4 * 4;
    FATOMIC(dst + 0, v.x); FATOMIC(dst + 1, v.y);
    FATOMIC(dst + 2, v.z); FATOMIC(dst + 3, v.w);
}

// ---------------- layer 0 GEMM: p = [nf | e2n] @ W0^T ; q = p ----------------
__global__ __launch_bounds__(256) void k_gemm0(const float* __restrict__ nf,
                                               const float* __restrict__ e2n,
                                               const float* __restrict__ W0,
                                               float* __restrict__ p, float* __restrict__ q)
{
    __shared__ float Ws[32 * 160];
    for (int t = threadIdx.x; t < 32 * 160; t += 256) Ws[t] = W0[t];
    __syncthreads();
    int i = blockIdx.x * 256 + threadIdx.x;
    if (i >= N_) return;
    float acc[32];
#pragma unroll
    for (int o = 0; o < 32; o++) acc[o] = 0.f;
    const float4* row  = reinterpret_cast<const float4*>(nf  + (long)i * NF_);
    const float4* row2 = reinterpret_cast<const float4*>(e2n + (long)i * EF_);
    const float4* Ws4  = reinterpret_cast<const float4*>(Ws);
    for (int d4 = 0; d4 < NF_ / 4; ++d4) {
        float4 v = row[d4];
#pragma unroll
        for (int o = 0; o < 32; o++) {
            float4 w = Ws4[o * 40 + d4];
            acc[o] += v.x * w.x + v.y * w.y + v.z * w.z + v.w * w.w;
        }
    }
#pragma unroll
    for (int d4 = 0; d4 < EF_ / 4; ++d4) {
        float4 v = row2[d4];
#pragma unroll
        for (int o = 0; o < 32; o++) {
            float4 w = Ws4[o * 40 + 32 + d4];
            acc[o] += v.x * w.x + v.y * w.y + v.z * w.z + v.w * w.w;
        }
    }
    float4* p4 = reinterpret_cast<float4*>(p + (long)i * 32);
    float4* q4 = reinterpret_cast<float4*>(q + (long)i * 32);
#pragma unroll
    for (int o4 = 0; o4 < 8; o4++) {
        float4 t = make_float4(acc[o4*4], acc[o4*4+1], acc[o4*4+2], acc[o4*4+3]);
        p4[o4] = t; q4[o4] = t;
    }
}

// ---------------- layers 1/2 GEMM: p = cat[:, off:off+32] @ W^T ; q = p ----------------
__global__ __launch_bounds__(256) void k_gemm32(const float* __restrict__ cat, int in_off,
                                                const float* __restrict__ W,
                                                float* __restrict__ p, float* __restrict__ q)
{
    __shared__ float Ws[32 * 32];
    for (int t = threadIdx.x; t < 1024; t += 256) Ws[t] = W[t];
    __syncthreads();
    int i = blockIdx.x * 256 + threadIdx.x;
    if (i >= N_) return;
    float acc[32];
#pragma unroll
    for (int o = 0; o < 32; o++) acc[o] = 0.f;
    const float4* row = reinterpret_cast<const float4*>(cat + (long)i * CATLD + in_off);
    const float4* Ws4 = reinterpret_cast<const float4*>(Ws);
#pragma unroll
    for (int d4 = 0; d4 < 8; ++d4) {
        float4 v = row[d4];
#pragma unroll
        for (int o = 0; o < 32; o++) {
            float4 w = Ws4[o * 8 + d4];
            acc[o] += v.x * w.x + v.y * w.y + v.z * w.z + v.w * w.w;
        }
    }
    float4* p4 = reinterpret_cast<float4*>(p + (long)i * 32);
    float4* q4 = reinterpret_cast<float4*>(q + (long)i * 32);
#pragma unroll
    for (int o4 = 0; o4 < 8; o4++) {
        float4 t = make_float4(acc[o4*4], acc[o4*4+1], acc[o4*4+2], acc[o4*4+3]);
        p4[o4] = t; q4[o4] = t;
    }
}

// ---------------- layer 3 GEMM: p1 = cat[:, 64:96] @ W3^T (D_out=1) ----------------
__global__ __launch_bounds__(256) void k_gemm1(const float* __restrict__ cat, int in_off,
                                               const float* __restrict__ W,
                                               float* __restrict__ p1, float* __restrict__ q1)
{
    int i = blockIdx.x * 256 + threadIdx.x;
    if (i >= N_) return;
    const float4* row = reinterpret_cast<const float4*>(cat + (long)i * CATLD + in_off);
    const float4* W4  = reinterpret_cast<const float4*>(W);
    float a = 0.f;
#pragma unroll
    for (int d4 = 0; d4 < 8; ++d4) {
        float4 v = row[d4]; float4 w = W4[d4];
        a += v.x * w.x + v.y * w.y + v.z * w.z + v.w * w.w;
    }
    p1[i] = a; q1[i] = a;
}

// ---------------- edge scatter (32-wide): q[row] += p[col] ----------------
__global__ __launch_bounds__(256) void k_scatter32(const int* __restrict__ erow,
                                                   const int* __restrict__ ecol,
                                                   const float* __restrict__ p,
                                                   float* __restrict__ q)
{
    int gid = blockIdx.x * 256 + threadIdx.x;      // E*8 threads
    int e = gid >> 3, o4 = gid & 7;
    int c = ecol[e], r = erow[e];
    float4 v = reinterpret_cast<const float4*>(p)[(long)c * 8 + o4];
    float* dst = q + (long)r * 32 + o4 * 4;
    FATOMIC(dst + 0, v.x); FATOMIC(dst + 1, v.y);
    FATOMIC(dst + 2, v.z); FATOMIC(dst + 3, v.w);
}

// ---------------- edge scatter (1-wide) ----------------
__global__ __launch_bounds__(256) void k_scatter1(const int* __restrict__ erow,
                                                  const int* __restrict__ ecol,
                                                  const float* __restrict__ p1,
                                                  float* __restrict__ q1)
{
    int e = blockIdx.x * 256 + threadIdx.x;        // E threads
    int c = ecol[e], r = erow[e];
    FATOMIC(q1 + r, p1[c]);
}

// ---------------- activation: cat[:, off:off+32] = tanh((q+b)/deg) ----------------
__global__ __launch_bounds__(256) void k_act32(const float* __restrict__ q,
                                               const float* __restrict__ b,
                                               const float* __restrict__ deg,
                                               float* __restrict__ cat, int out_off)
{
    int gid = blockIdx.x * 256 + threadIdx.x;      // N*32 threads
    int i = gid >> 5, o = gid & 31;
    float v = tanhf((q[gid] + b[o]) / deg[i]);
    cat[(long)i * CATLD + out_off + o] = v;
}

__global__ __launch_bounds__(256) void k_act1(const float* __restrict__ q1,
                                              const float* __restrict__ b,
                                              const float* __restrict__ deg,
                                              float* __restrict__ cat)
{
    int i = blockIdx.x * 256 + threadIdx.x;        // N threads
    cat[(long)i * CATLD + 96] = tanhf((q1[i] + b[0]) / deg[i]);
}

// ---------------- sortpooling top-K + conv/MLP head (one block per graph) ----------------
__global__ __launch_bounds__(256) void k_topk_head(
    const float* __restrict__ cat,
    const float* __restrict__ Wc1, const float* __restrict__ bc1,
    const float* __restrict__ Wc2, const float* __restrict__ bc2,
    const float* __restrict__ Wh,  const float* __restrict__ bh,
    const float* __restrict__ Wo,  const float* __restrict__ bo,
    float* __restrict__ out)
{
    const int g = blockIdx.x, tid = threadIdx.x;
    __shared__ float vals[NPG_];
    __shared__ int   sel[K_];
    __shared__ float Pm[K_][TLD_];
    __shared__ float redv[4]; __shared__ int redi[4];
    __shared__ float y1[C1_][K_];
    __shared__ float y2[C1_][P2_];
    __shared__ float dd[DENSE_];
    __shared__ float h1s[HID_];
    __shared__ float zz[NCLS_];
    const long gbase = (long)g * NPG_;

    for (int j = tid; j < NPG_; j += 256) vals[j] = cat[(gbase + j) * CATLD + 96];
    __syncthreads();

    // iterative argmax, K times; ties -> lower index (jax.lax.top_k semantics)
    for (int k = 0; k < K_; k++) {
        float bv = -INFINITY; int bi = NPG_;
        for (int j = tid; j < NPG_; j += 256) {
            float v = vals[j];
            if (v > bv) { bv = v; bi = j; }        // j increasing: strict > keeps lower idx on ties
        }
#pragma unroll
        for (int s = 32; s > 0; s >>= 1) {
            float ov = __shfl_down(bv, s); int oi = __shfl_down(bi, s);
            if (ov > bv || (ov == bv && oi < bi)) { bv = ov; bi = oi; }
        }
        if ((tid & 63) == 0) { redv[tid >> 6] = bv; redi[tid >> 6] = bi; }
        __syncthreads();
        if (tid == 0) {
            for (int w = 1; w < 4; w++)
                if (redv[w] > bv || (redv[w] == bv && redi[w] < bi)) { bv = redv[w]; bi = redi[w]; }
            sel[k] = bi; vals[bi] = -INFINITY;
        }
        __syncthreads();
    }

    // gather the K selected 97-dim rows
    for (int t = tid; t < K_ * TLD_; t += 256) {
        int k = t / TLD_, d = t % TLD_;
        Pm[k][d] = cat[(gbase + sel[k]) * CATLD + d];
    }
    __syncthreads();

    // conv1 (per-node linear) + relu
    for (int t = tid; t < C1_ * K_; t += 256) {
        int c = t / K_, k = t % K_;
        float a = bc1[c];
        for (int d = 0; d < TLD_; d++) a += Pm[k][d] * Wc1[c * TLD_ + d];
        y1[c][k] = fmaxf(a, 0.f);
    }
    __syncthreads();

    // maxpool(2,2)
    for (int t = tid; t < C1_ * P2_; t += 256) {
        int c = t / P2_, u = t % P2_;
        y2[c][u] = fmaxf(y1[c][2 * u], y1[c][2 * u + 1]);
    }
    __syncthreads();

    // conv2 (valid, kw=5) + relu  -> dd flattened [C2][U]
    for (int t = tid; t < C2_ * U_; t += 256) {
        int c2 = t / U_, u = t % U_;
        float a = bc2[c2];
        for (int c = 0; c < C1_; c++)
#pragma unroll
            for (int w = 0; w < KW2_; w++)
                a += y2[c][u + w] * Wc2[(c2 * C1_ + c) * KW2_ + w];
        dd[t] = fmaxf(a, 0.f);
    }
    __syncthreads();

    // hidden dense + relu
    if (tid < HID_) {
        float a = bh[tid];
        for (int i = 0; i < DENSE_; i++) a += dd[i] * Wh[tid * DENSE_ + i];
        h1s[tid] = fmaxf(a, 0.f);
    }
    __syncthreads();

    // output dense
    if (tid < NCLS_) {
        float a = bo[tid];
        for (int j = 0; j < HID_; j++) a += h1s[j] * Wo[tid * HID_ + j];
        zz[tid] = a;
    }
    __syncthreads();

    // log_softmax
    if (tid == 0) {
        float m = zz[0];
        for (int c = 1; c < NCLS_; c++) m = fmaxf(m, zz[c]);
        float s = 0.f;
        for (int c = 0; c < NCLS_; c++) s += expf(zz[c] - m);
        float lse = m + logf(s);
        for (int c = 0; c < NCLS_; c++) out[g * NCLS_ + c] = zz[c] - lse;
    }
}

// ---------------- host launch ----------------
extern "C" void kernel_launch(void* const* d_in, const int* in_sizes, int n_in,
                              void* d_out, int out_size, void* d_ws, size_t ws_size,
                              hipStream_t stream)
{
    const float* nf  = (const float*)d_in[0];
    const float* ef  = (const float*)d_in[1];
    const float* deg = (const float*)d_in[2];
    const float* W0  = (const float*)d_in[3];  const float* b0  = (const float*)d_in[4];
    const float* W1  = (const float*)d_in[5];  const float* b1  = (const float*)d_in[6];
    const float* W2  = (const float*)d_in[7];  const float* b2  = (const float*)d_in[8];
    const float* W3  = (const float*)d_in[9];  const float* b3  = (const float*)d_in[10];
    const float* Wc1 = (const float*)d_in[11]; const float* bc1 = (const float*)d_in[12];
    const float* Wc2 = (const float*)d_in[13]; const float* bc2 = (const float*)d_in[14];
    const float* Wh  = (const float*)d_in[15]; const float* bh  = (const float*)d_in[16];
    const float* Wo  = (const float*)d_in[17]; const float* bo  = (const float*)d_in[18];
    const int* erow  = (const int*)d_in[19];
    const int* ecol  = (const int*)d_in[20];
    float* out = (float*)d_out;

    float* ws  = (float*)d_ws;
    float* e2n = ws;                         // N*32
    float* p   = e2n + (long)N_ * 32;        // N*32
    float* q   = p   + (long)N_ * 32;        // N*32
    float* cat = q   + (long)N_ * 32;        // N*128

    (void)hipMemsetAsync(e2n, 0, (size_t)N_ * 32 * sizeof(float), stream);
    k_e2n_scatter<<<E_ * 8 / 256, 256, 0, stream>>>((const float4*)ef, erow, e2n);

    // layer 0
    k_gemm0<<<N_ / 256, 256, 0, stream>>>(nf, e2n, W0, p, q);
    k_scatter32<<<E_ * 8 / 256, 256, 0, stream>>>(erow, ecol, p, q);
    k_act32<<<N_ * 32 / 256, 256, 0, stream>>>(q, b0, deg, cat, 0);
    // layer 1
    k_gemm32<<<N_ / 256, 256, 0, stream>>>(cat, 0, W1, p, q);
    k_scatter32<<<E_ * 8 / 256, 256, 0, stream>>>(erow, ecol, p, q);
    k_act32<<<N_ * 32 / 256, 256, 0, stream>>>(q, b1, deg, cat, 32);
    // layer 2
    k_gemm32<<<N_ / 256, 256, 0, stream>>>(cat, 32, W2, p, q);
    k_scatter32<<<E_ * 8 / 256, 256, 0, stream>>>(erow, ecol, p, q);
    k_act32<<<N_ * 32 / 256, 256, 0, stream>>>(q, b2, deg, cat, 64);
    // layer 3 (D_out = 1)
    k_gemm1<<<N_ / 256, 256, 0, stream>>>(cat, 64, W3, p, q);
    k_scatter1<<<E_ / 256, 256, 0, stream>>>(erow, ecol, p, q);
    k_act1<<<N_ / 256, 256, 0, stream>>>(q, b3, deg, cat);

    // sortpooling + head
    k_topk_head<<<B_, 256, 0, stream>>>(cat, Wc1, bc1, Wc2, bc2, Wh, bh, Wo, bo, out);
}

// Round 2
// 739.082 us; speedup vs baseline: 4.9669x; 4.9669x over previous
//
#include <hip/hip_runtime.h>
#include <math.h>

// ---------------- problem constants ----------------
constexpr int B_    = 64;
constexpr int NPG_  = 2048;
constexpr int N_    = B_ * NPG_;        // 131072
constexpr int E_    = N_ * 16;          // 2097152
constexpr int NF_   = 128;
constexpr int EF_   = 32;
constexpr int TLD_  = 97;
constexpr int K_    = 30;
constexpr int C1_   = 16;
constexpr int C2_   = 32;
constexpr int KW2_  = 5;
constexpr int P2_   = 15;
constexpr int U_    = 11;
constexpr int DENSE_= C2_ * U_;         // 352
constexpr int HID_  = 128;
constexpr int NCLS_ = 10;
constexpr int CATLD = 128;              // padded leading dim for cat[N][97]

__device__ __forceinline__ int cnt_of(float d) { return (int)(d + 0.5f) - 1; }

// ---------------- CSR build: scan of (deg-1) ----------------
// scan1: 128 blocks x 1024 elements; per-block exclusive scan + block totals
__global__ __launch_bounds__(256) void k_scan1(const float* __restrict__ deg,
                                               int* __restrict__ part,
                                               int* __restrict__ bsum)
{
    const int t = threadIdx.x;
    const int base = blockIdx.x * 1024 + t * 4;
    int c0 = cnt_of(deg[base + 0]);
    int c1 = cnt_of(deg[base + 1]);
    int c2 = cnt_of(deg[base + 2]);
    int c3 = cnt_of(deg[base + 3]);
    int s = c0 + c1 + c2 + c3;
    int lane = t & 63, w = t >> 6;
    int sc = s;
#pragma unroll
    for (int d = 1; d < 64; d <<= 1) {
        int v = __shfl_up(sc, d);
        if (lane >= d) sc += v;
    }
    __shared__ int wsum[4];
    if (lane == 63) wsum[w] = sc;
    __syncthreads();
    int woff = 0;
    for (int k = 0; k < w; k++) woff += wsum[k];
    int excl = woff + sc - s;
    part[base + 0] = excl;
    part[base + 1] = excl + c0;
    part[base + 2] = excl + c0 + c1;
    part[base + 3] = excl + c0 + c1 + c2;
    if (t == 255) bsum[blockIdx.x] = woff + sc;
}

// scan2: single block, exclusive scan of 128 block sums
__global__ __launch_bounds__(128) void k_scan2(int* __restrict__ bsum)
{
    __shared__ int sh[128];
    int t = threadIdx.x;
    sh[t] = bsum[t];
    __syncthreads();
    if (t == 0) {
        int acc = 0;
        for (int i = 0; i < 128; i++) { int v = sh[i]; sh[i] = acc; acc += v; }
    }
    __syncthreads();
    bsum[t] = sh[t];
}

// scan3: add block offsets; produce row_start and cursor copy
__global__ __launch_bounds__(256) void k_scan3(int* __restrict__ part,
                                               const int* __restrict__ bsum,
                                               int* __restrict__ cursor)
{
    int i = blockIdx.x * 256 + threadIdx.x;
    int v = part[i] + bsum[i >> 10];
    part[i] = v;
    cursor[i] = v;
}

// fill: bucket each edge into its row's slot
__global__ __launch_bounds__(256) void k_fill(const int* __restrict__ erow,
                                              const int* __restrict__ ecol,
                                              int* __restrict__ cursor,
                                              int* __restrict__ adjc,
                                              int* __restrict__ adje)
{
    int e = blockIdx.x * 256 + threadIdx.x;
    int r = erow[e];
    int slot = atomicAdd(&cursor[r], 1);
    adjc[slot] = ecol[e];
    adje[slot] = e;
}

// ---------------- e2n gather: e2n[i][o] = sum_{e in row i} ef[e][o] ----------------
__global__ __launch_bounds__(256) void k_e2n_gather(const float* __restrict__ ef,
                                                    const int* __restrict__ row_start,
                                                    const float* __restrict__ deg,
                                                    const int* __restrict__ adje,
                                                    float* __restrict__ e2n)
{
    int gid = blockIdx.x * 256 + threadIdx.x;   // N*32 threads
    int i = gid >> 5, o = gid & 31;
    int s = row_start[i];
    int n = cnt_of(deg[i]);
    float a = 0.f;
    for (int k = 0; k < n; k++) {
        int eid = adje[s + k];
        a += ef[(long)eid * EF_ + o];
    }
    e2n[gid] = a;
}

// ---------------- layer 0 GEMM: p = [nf | e2n] @ W0^T ----------------
__global__ __launch_bounds__(256) void k_gemm0(const float* __restrict__ nf,
                                               const float* __restrict__ e2n,
                                               const float* __restrict__ W0,
                                               float* __restrict__ p)
{
    __shared__ float Ws[32 * 160];
    for (int t = threadIdx.x; t < 32 * 160; t += 256) Ws[t] = W0[t];
    __syncthreads();
    int i = blockIdx.x * 256 + threadIdx.x;
    float acc[32];
#pragma unroll
    for (int o = 0; o < 32; o++) acc[o] = 0.f;
    const float4* row  = reinterpret_cast<const float4*>(nf  + (long)i * NF_);
    const float4* row2 = reinterpret_cast<const float4*>(e2n + (long)i * EF_);
    const float4* Ws4  = reinterpret_cast<const float4*>(Ws);
    for (int d4 = 0; d4 < NF_ / 4; ++d4) {
        float4 v = row[d4];
#pragma unroll
        for (int o = 0; o < 32; o++) {
            float4 w = Ws4[o * 40 + d4];
            acc[o] += v.x * w.x + v.y * w.y + v.z * w.z + v.w * w.w;
        }
    }
#pragma unroll
    for (int d4 = 0; d4 < EF_ / 4; ++d4) {
        float4 v = row2[d4];
#pragma unroll
        for (int o = 0; o < 32; o++) {
            float4 w = Ws4[o * 40 + 32 + d4];
            acc[o] += v.x * w.x + v.y * w.y + v.z * w.z + v.w * w.w;
        }
    }
    float4* p4 = reinterpret_cast<float4*>(p + (long)i * 32);
#pragma unroll
    for (int o4 = 0; o4 < 8; o4++)
        p4[o4] = make_float4(acc[o4*4], acc[o4*4+1], acc[o4*4+2], acc[o4*4+3]);
}

// ---------------- layers 1/2 GEMM: p = cat[:, off:off+32] @ W^T ----------------
__global__ __launch_bounds__(256) void k_gemm32(const float* __restrict__ cat, int in_off,
                                                const float* __restrict__ W,
                                                float* __restrict__ p)
{
    __shared__ float Ws[32 * 32];
    for (int t = threadIdx.x; t < 1024; t += 256) Ws[t] = W[t];
    __syncthreads();
    int i = blockIdx.x * 256 + threadIdx.x;
    float acc[32];
#pragma unroll
    for (int o = 0; o < 32; o++) acc[o] = 0.f;
    const float4* row = reinterpret_cast<const float4*>(cat + (long)i * CATLD + in_off);
    const float4* Ws4 = reinterpret_cast<const float4*>(Ws);
#pragma unroll
    for (int d4 = 0; d4 < 8; ++d4) {
        float4 v = row[d4];
#pragma unroll
        for (int o = 0; o < 32; o++) {
            float4 w = Ws4[o * 8 + d4];
            acc[o] += v.x * w.x + v.y * w.y + v.z * w.z + v.w * w.w;
        }
    }
    float4* p4 = reinterpret_cast<float4*>(p + (long)i * 32);
#pragma unroll
    for (int o4 = 0; o4 < 8; o4++)
        p4[o4] = make_float4(acc[o4*4], acc[o4*4+1], acc[o4*4+2], acc[o4*4+3]);
}

// ---------------- layer 3 GEMM: p1 = cat[:, 64:96] @ W3^T (D_out=1) ----------------
__global__ __launch_bounds__(256) void k_gemm1(const float* __restrict__ cat, int in_off,
                                               const float* __restrict__ W,
                                               float* __restrict__ p1)
{
    int i = blockIdx.x * 256 + threadIdx.x;
    const float4* row = reinterpret_cast<const float4*>(cat + (long)i * CATLD + in_off);
    const float4* W4  = reinterpret_cast<const float4*>(W);
    float a = 0.f;
#pragma unroll
    for (int d4 = 0; d4 < 8; ++d4) {
        float4 v = row[d4]; float4 w = W4[d4];
        a += v.x * w.x + v.y * w.y + v.z * w.z + v.w * w.w;
    }
    p1[i] = a;
}

// ---------------- fused gather + activation (32-wide) ----------------
// cat[:, off+o] = tanh((p[i][o] + sum_{e in row i} p[col(e)][o] + b[o]) / deg[i])
__global__ __launch_bounds__(256) void k_gather_act32(const int* __restrict__ row_start,
                                                      const int* __restrict__ adjc,
                                                      const float* __restrict__ deg,
                                                      const float* __restrict__ p,
                                                      const float* __restrict__ b,
                                                      float* __restrict__ cat, int out_off)
{
    int gid = blockIdx.x * 256 + threadIdx.x;   // N*32 threads
    int i = gid >> 5, o = gid & 31;
    int s = row_start[i];
    float dg = deg[i];
    int n = cnt_of(dg);
    float a = p[gid];
    for (int k = 0; k < n; k++) {
        int c = adjc[s + k];
        a += p[(long)c * 32 + o];
    }
    cat[(long)i * CATLD + out_off + o] = tanhf((a + b[o]) / dg);
}

// ---------------- fused gather + activation (1-wide, layer 3) ----------------
__global__ __launch_bounds__(256) void k_gather_act1(const int* __restrict__ row_start,
                                                     const int* __restrict__ adjc,
                                                     const float* __restrict__ deg,
                                                     const float* __restrict__ p1,
                                                     const float* __restrict__ b,
                                                     float* __restrict__ cat)
{
    int i = blockIdx.x * 256 + threadIdx.x;     // N threads
    int s = row_start[i];
    float dg = deg[i];
    int n = cnt_of(dg);
    float a = p1[i];
    for (int k = 0; k < n; k++) a += p1[adjc[s + k]];
    cat[(long)i * CATLD + 96] = tanhf((a + b[0]) / dg);
}

// ---------------- sortpooling top-K + conv/MLP head (one block per graph) ----------------
__global__ __launch_bounds__(256) void k_topk_head(
    const float* __restrict__ cat,
    const float* __restrict__ Wc1, const float* __restrict__ bc1,
    const float* __restrict__ Wc2, const float* __restrict__ bc2,
    const float* __restrict__ Wh,  const float* __restrict__ bh,
    const float* __restrict__ Wo,  const float* __restrict__ bo,
    float* __restrict__ out)
{
    const int g = blockIdx.x, tid = threadIdx.x;
    __shared__ float vals[NPG_];
    __shared__ int   sel[K_];
    __shared__ float Pm[K_][TLD_];
    __shared__ float redv[4]; __shared__ int redi[4];
    __shared__ float y1[C1_][K_];
    __shared__ float y2[C1_][P2_];
    __shared__ float dd[DENSE_];
    __shared__ float h1s[HID_];
    __shared__ float zz[NCLS_];
    const long gbase = (long)g * NPG_;

    for (int j = tid; j < NPG_; j += 256) vals[j] = cat[(gbase + j) * CATLD + 96];
    __syncthreads();

    // iterative argmax, K times; ties -> lower index (jax.lax.top_k semantics)
    for (int k = 0; k < K_; k++) {
        float bv = -INFINITY; int bi = NPG_;
        for (int j = tid; j < NPG_; j += 256) {
            float v = vals[j];
            if (v > bv) { bv = v; bi = j; }
        }
#pragma unroll
        for (int s = 32; s > 0; s >>= 1) {
            float ov = __shfl_down(bv, s); int oi = __shfl_down(bi, s);
            if (ov > bv || (ov == bv && oi < bi)) { bv = ov; bi = oi; }
        }
        if ((tid & 63) == 0) { redv[tid >> 6] = bv; redi[tid >> 6] = bi; }
        __syncthreads();
        if (tid == 0) {
            for (int w = 1; w < 4; w++)
                if (redv[w] > bv || (redv[w] == bv && redi[w] < bi)) { bv = redv[w]; bi = redi[w]; }
            sel[k] = bi; vals[bi] = -INFINITY;
        }
        __syncthreads();
    }

    for (int t = tid; t < K_ * TLD_; t += 256) {
        int k = t / TLD_, d = t % TLD_;
        Pm[k][d] = cat[(gbase + sel[k]) * CATLD + d];
    }
    __syncthreads();

    for (int t = tid; t < C1_ * K_; t += 256) {
        int c = t / K_, k = t % K_;
        float a = bc1[c];
        for (int d = 0; d < TLD_; d++) a += Pm[k][d] * Wc1[c * TLD_ + d];
        y1[c][k] = fmaxf(a, 0.f);
    }
    __syncthreads();

    for (int t = tid; t < C1_ * P2_; t += 256) {
        int c = t / P2_, u = t % P2_;
        y2[c][u] = fmaxf(y1[c][2 * u], y1[c][2 * u + 1]);
    }
    __syncthreads();

    for (int t = tid; t < C2_ * U_; t += 256) {
        int c2 = t / U_, u = t % U_;
        float a = bc2[c2];
        for (int c = 0; c < C1_; c++)
#pragma unroll
            for (int w = 0; w < KW2_; w++)
                a += y2[c][u + w] * Wc2[(c2 * C1_ + c) * KW2_ + w];
        dd[t] = fmaxf(a, 0.f);
    }
    __syncthreads();

    if (tid < HID_) {
        float a = bh[tid];
        for (int i = 0; i < DENSE_; i++) a += dd[i] * Wh[tid * DENSE_ + i];
        h1s[tid] = fmaxf(a, 0.f);
    }
    __syncthreads();

    if (tid < NCLS_) {
        float a = bo[tid];
        for (int j = 0; j < HID_; j++) a += h1s[j] * Wo[tid * HID_ + j];
        zz[tid] = a;
    }
    __syncthreads();

    if (tid == 0) {
        float m = zz[0];
        for (int c = 1; c < NCLS_; c++) m = fmaxf(m, zz[c]);
        float s = 0.f;
        for (int c = 0; c < NCLS_; c++) s += expf(zz[c] - m);
        float lse = m + logf(s);
        for (int c = 0; c < NCLS_; c++) out[g * NCLS_ + c] = zz[c] - lse;
    }
}

// ---------------- host launch ----------------
extern "C" void kernel_launch(void* const* d_in, const int* in_sizes, int n_in,
                              void* d_out, int out_size, void* d_ws, size_t ws_size,
                              hipStream_t stream)
{
    const float* nf  = (const float*)d_in[0];
    const float* ef  = (const float*)d_in[1];
    const float* deg = (const float*)d_in[2];
    const float* W0  = (const float*)d_in[3];  const float* b0  = (const float*)d_in[4];
    const float* W1  = (const float*)d_in[5];  const float* b1  = (const float*)d_in[6];
    const float* W2  = (const float*)d_in[7];  const float* b2  = (const float*)d_in[8];
    const float* W3  = (const float*)d_in[9];  const float* b3  = (const float*)d_in[10];
    const float* Wc1 = (const float*)d_in[11]; const float* bc1 = (const float*)d_in[12];
    const float* Wc2 = (const float*)d_in[13]; const float* bc2 = (const float*)d_in[14];
    const float* Wh  = (const float*)d_in[15]; const float* bh  = (const float*)d_in[16];
    const float* Wo  = (const float*)d_in[17]; const float* bo  = (const float*)d_in[18];
    const int* erow  = (const int*)d_in[19];
    const int* ecol  = (const int*)d_in[20];
    float* out = (float*)d_out;

    // ---- workspace layout ----
    char* wsb = (char*)d_ws;
    float* e2n       = (float*)wsb;                       wsb += (size_t)N_ * 32 * 4;   // 16 MB
    float* p         = (float*)wsb;                       wsb += (size_t)N_ * 32 * 4;   // 16 MB (also p1)
    float* cat       = (float*)wsb;                       wsb += (size_t)N_ * CATLD * 4;// 64 MB
    int*   row_start = (int*)wsb;                         wsb += (size_t)N_ * 4;
    int*   cursor    = (int*)wsb;                         wsb += (size_t)N_ * 4;
    int*   bsum      = (int*)wsb;                         wsb += 128 * 4;
    int*   adjc      = (int*)wsb;                         wsb += (size_t)E_ * 4;        // 8 MB
    int*   adje      = (int*)wsb;                         /* 8 MB */

    // ---- CSR build (counts derived from node_degs = cnt+1) ----
    k_scan1<<<N_ / 1024, 256, 0, stream>>>(deg, row_start, bsum);
    k_scan2<<<1, 128, 0, stream>>>(bsum);
    k_scan3<<<N_ / 256, 256, 0, stream>>>(row_start, bsum, cursor);
    k_fill<<<E_ / 256, 256, 0, stream>>>(erow, ecol, cursor, adjc, adje);

    // ---- e2n via gather ----
    k_e2n_gather<<<N_ * 32 / 256, 256, 0, stream>>>(ef, row_start, deg, adje, e2n);

    // ---- layer 0 ----
    k_gemm0<<<N_ / 256, 256, 0, stream>>>(nf, e2n, W0, p);
    k_gather_act32<<<N_ * 32 / 256, 256, 0, stream>>>(row_start, adjc, deg, p, b0, cat, 0);
    // ---- layer 1 ----
    k_gemm32<<<N_ / 256, 256, 0, stream>>>(cat, 0, W1, p);
    k_gather_act32<<<N_ * 32 / 256, 256, 0, stream>>>(row_start, adjc, deg, p, b1, cat, 32);
    // ---- layer 2 ----
    k_gemm32<<<N_ / 256, 256, 0, stream>>>(cat, 32, W2, p);
    k_gather_act32<<<N_ * 32 / 256, 256, 0, stream>>>(row_start, adjc, deg, p, b2, cat, 64);
    // ---- layer 3 (D_out = 1, pre-projected) ----
    k_gemm1<<<N_ / 256, 256, 0, stream>>>(cat, 64, W3, p);
    k_gather_act1<<<N_ / 256, 256, 0, stream>>>(row_start, adjc, deg, p, b3, cat);

    // ---- sortpooling + head ----
    k_topk_head<<<B_, 256, 0, stream>>>(cat, Wc1, bc1, Wc2, bc2, Wh, bh, Wo, bo, out);
}

// Round 3
// 493.877 us; speedup vs baseline: 7.4329x; 1.4965x over previous
//
#include <hip/hip_runtime.h>
#include <math.h>

// ---------------- problem constants ----------------
constexpr int B_    = 64;
constexpr int NPG_  = 2048;
constexpr int N_    = B_ * NPG_;        // 131072
constexpr int E_    = N_ * 16;          // 2097152
constexpr int NF_   = 128;
constexpr int EF_   = 32;
constexpr int TLD_  = 97;
constexpr int K_    = 30;
constexpr int C1_   = 16;
constexpr int C2_   = 32;
constexpr int KW2_  = 5;
constexpr int P2_   = 15;
constexpr int U_    = 11;
constexpr int DENSE_= C2_ * U_;         // 352
constexpr int HID_  = 128;
constexpr int NCLS_ = 10;
constexpr int CATLD = 128;              // padded leading dim for cat[N][97]

__device__ __forceinline__ int cnt_of(float d) { return (int)(d + 0.5f) - 1; }

// ---------------- CSR build: scan of (deg-1) ----------------
__global__ __launch_bounds__(256) void k_scan1(const float* __restrict__ deg,
                                               int* __restrict__ part,
                                               int* __restrict__ bsum)
{
    const int t = threadIdx.x;
    const int base = blockIdx.x * 1024 + t * 4;
    int c0 = cnt_of(deg[base + 0]);
    int c1 = cnt_of(deg[base + 1]);
    int c2 = cnt_of(deg[base + 2]);
    int c3 = cnt_of(deg[base + 3]);
    int s = c0 + c1 + c2 + c3;
    int lane = t & 63, w = t >> 6;
    int sc = s;
#pragma unroll
    for (int d = 1; d < 64; d <<= 1) {
        int v = __shfl_up(sc, d);
        if (lane >= d) sc += v;
    }
    __shared__ int wsum[4];
    if (lane == 63) wsum[w] = sc;
    __syncthreads();
    int woff = 0;
    for (int k = 0; k < w; k++) woff += wsum[k];
    int excl = woff + sc - s;
    part[base + 0] = excl;
    part[base + 1] = excl + c0;
    part[base + 2] = excl + c0 + c1;
    part[base + 3] = excl + c0 + c1 + c2;
    if (t == 255) bsum[blockIdx.x] = woff + sc;
}

__global__ __launch_bounds__(128) void k_scan2(int* __restrict__ bsum)
{
    __shared__ int sh[128];
    int t = threadIdx.x;
    sh[t] = bsum[t];
    __syncthreads();
    if (t == 0) {
        int acc = 0;
        for (int i = 0; i < 128; i++) { int v = sh[i]; sh[i] = acc; acc += v; }
    }
    __syncthreads();
    bsum[t] = sh[t];
}

__global__ __launch_bounds__(256) void k_scan3(int* __restrict__ part,
                                               const int* __restrict__ bsum,
                                               int* __restrict__ cursor)
{
    int i = blockIdx.x * 256 + threadIdx.x;
    int v = part[i] + bsum[i >> 10];
    part[i] = v;
    cursor[i] = v;
}

__global__ __launch_bounds__(256) void k_fill(const int* __restrict__ erow,
                                              const int* __restrict__ ecol,
                                              int* __restrict__ cursor,
                                              int* __restrict__ adjc,
                                              int* __restrict__ adje)
{
    int e = blockIdx.x * 256 + threadIdx.x;
    int r = erow[e];
    int slot = atomicAdd(&cursor[r], 1);
    adjc[slot] = ecol[e];
    adje[slot] = e;
}

// ---------------- e2n gather (chunk-8 MLP): e2n[i][o] = sum_{e in row i} ef[e][o] ----------------
__global__ __launch_bounds__(256) void k_e2n_gather(const float* __restrict__ ef,
                                                    const int* __restrict__ row_start,
                                                    const float* __restrict__ deg,
                                                    const int* __restrict__ adje,
                                                    float* __restrict__ e2n)
{
    int gid = blockIdx.x * 256 + threadIdx.x;   // N*32 threads
    int i = gid >> 5, o = gid & 31;
    int s = row_start[i];
    int n = cnt_of(deg[i]);
    float a = 0.f;
    int k = 0;
    for (; k + 8 <= n; k += 8) {
        int e0 = adje[s + k + 0], e1 = adje[s + k + 1], e2 = adje[s + k + 2], e3 = adje[s + k + 3];
        int e4 = adje[s + k + 4], e5 = adje[s + k + 5], e6 = adje[s + k + 6], e7 = adje[s + k + 7];
        float v0 = ef[(long)e0 * EF_ + o], v1 = ef[(long)e1 * EF_ + o];
        float v2 = ef[(long)e2 * EF_ + o], v3 = ef[(long)e3 * EF_ + o];
        float v4 = ef[(long)e4 * EF_ + o], v5 = ef[(long)e5 * EF_ + o];
        float v6 = ef[(long)e6 * EF_ + o], v7 = ef[(long)e7 * EF_ + o];
        a += ((v0 + v1) + (v2 + v3)) + ((v4 + v5) + (v6 + v7));
    }
    for (; k < n; k++) a += ef[(long)adje[s + k] * EF_ + o];
    e2n[gid] = a;
}

// ---------------- layer 0 GEMM: p = [nf | e2n] @ W0^T ----------------
__global__ __launch_bounds__(256) void k_gemm0(const float* __restrict__ nf,
                                               const float* __restrict__ e2n,
                                               const float* __restrict__ W0,
                                               float* __restrict__ p)
{
    __shared__ float Ws[32 * 160];
    for (int t = threadIdx.x; t < 32 * 160; t += 256) Ws[t] = W0[t];
    __syncthreads();
    int i = blockIdx.x * 256 + threadIdx.x;
    float acc[32];
#pragma unroll
    for (int o = 0; o < 32; o++) acc[o] = 0.f;
    const float4* row  = reinterpret_cast<const float4*>(nf  + (long)i * NF_);
    const float4* row2 = reinterpret_cast<const float4*>(e2n + (long)i * EF_);
    const float4* Ws4  = reinterpret_cast<const float4*>(Ws);
    for (int d4 = 0; d4 < NF_ / 4; ++d4) {
        float4 v = row[d4];
#pragma unroll
        for (int o = 0; o < 32; o++) {
            float4 w = Ws4[o * 40 + d4];
            acc[o] += v.x * w.x + v.y * w.y + v.z * w.z + v.w * w.w;
        }
    }
#pragma unroll
    for (int d4 = 0; d4 < EF_ / 4; ++d4) {
        float4 v = row2[d4];
#pragma unroll
        for (int o = 0; o < 32; o++) {
            float4 w = Ws4[o * 40 + 32 + d4];
            acc[o] += v.x * w.x + v.y * w.y + v.z * w.z + v.w * w.w;
        }
    }
    float4* p4 = reinterpret_cast<float4*>(p + (long)i * 32);
#pragma unroll
    for (int o4 = 0; o4 < 8; o4++)
        p4[o4] = make_float4(acc[o4*4], acc[o4*4+1], acc[o4*4+2], acc[o4*4+3]);
}

// ---------------- layers 1/2 GEMM: p = cat[:, off:off+32] @ W^T ----------------
__global__ __launch_bounds__(256) void k_gemm32(const float* __restrict__ cat, int in_off,
                                                const float* __restrict__ W,
                                                float* __restrict__ p)
{
    __shared__ float Ws[32 * 32];
    for (int t = threadIdx.x; t < 1024; t += 256) Ws[t] = W[t];
    __syncthreads();
    int i = blockIdx.x * 256 + threadIdx.x;
    float acc[32];
#pragma unroll
    for (int o = 0; o < 32; o++) acc[o] = 0.f;
    const float4* row = reinterpret_cast<const float4*>(cat + (long)i * CATLD + in_off);
    const float4* Ws4 = reinterpret_cast<const float4*>(Ws);
#pragma unroll
    for (int d4 = 0; d4 < 8; ++d4) {
        float4 v = row[d4];
#pragma unroll
        for (int o = 0; o < 32; o++) {
            float4 w = Ws4[o * 8 + d4];
            acc[o] += v.x * w.x + v.y * w.y + v.z * w.z + v.w * w.w;
        }
    }
    float4* p4 = reinterpret_cast<float4*>(p + (long)i * 32);
#pragma unroll
    for (int o4 = 0; o4 < 8; o4++)
        p4[o4] = make_float4(acc[o4*4], acc[o4*4+1], acc[o4*4+2], acc[o4*4+3]);
}

// ---------------- layer 3 GEMM: p1 = cat[:, 64:96] @ W3^T (D_out=1) ----------------
__global__ __launch_bounds__(256) void k_gemm1(const float* __restrict__ cat, int in_off,
                                               const float* __restrict__ W,
                                               float* __restrict__ p1)
{
    int i = blockIdx.x * 256 + threadIdx.x;
    const float4* row = reinterpret_cast<const float4*>(cat + (long)i * CATLD + in_off);
    const float4* W4  = reinterpret_cast<const float4*>(W);
    float a = 0.f;
#pragma unroll
    for (int d4 = 0; d4 < 8; ++d4) {
        float4 v = row[d4]; float4 w = W4[d4];
        a += v.x * w.x + v.y * w.y + v.z * w.z + v.w * w.w;
    }
    p1[i] = a;
}

// ---------------- fused gather + activation (32-wide, chunk-8 MLP) ----------------
__global__ __launch_bounds__(256) void k_gather_act32(const int* __restrict__ row_start,
                                                      const int* __restrict__ adjc,
                                                      const float* __restrict__ deg,
                                                      const float* __restrict__ p,
                                                      const float* __restrict__ b,
                                                      float* __restrict__ cat, int out_off)
{
    int gid = blockIdx.x * 256 + threadIdx.x;   // N*32 threads
    int i = gid >> 5, o = gid & 31;
    int s = row_start[i];
    float dg = deg[i];
    int n = cnt_of(dg);
    float a = p[gid];
    int k = 0;
    for (; k + 8 <= n; k += 8) {
        int c0 = adjc[s + k + 0], c1 = adjc[s + k + 1], c2 = adjc[s + k + 2], c3 = adjc[s + k + 3];
        int c4 = adjc[s + k + 4], c5 = adjc[s + k + 5], c6 = adjc[s + k + 6], c7 = adjc[s + k + 7];
        float v0 = p[(long)c0 * 32 + o], v1 = p[(long)c1 * 32 + o];
        float v2 = p[(long)c2 * 32 + o], v3 = p[(long)c3 * 32 + o];
        float v4 = p[(long)c4 * 32 + o], v5 = p[(long)c5 * 32 + o];
        float v6 = p[(long)c6 * 32 + o], v7 = p[(long)c7 * 32 + o];
        a += ((v0 + v1) + (v2 + v3)) + ((v4 + v5) + (v6 + v7));
    }
    for (; k < n; k++) a += p[(long)adjc[s + k] * 32 + o];
    cat[(long)i * CATLD + out_off + o] = tanhf((a + b[o]) / dg);
}

// ---------------- fused gather + activation (1-wide, layer 3, chunk-8 MLP) ----------------
__global__ __launch_bounds__(256) void k_gather_act1(const int* __restrict__ row_start,
                                                     const int* __restrict__ adjc,
                                                     const float* __restrict__ deg,
                                                     const float* __restrict__ p1,
                                                     const float* __restrict__ b,
                                                     float* __restrict__ cat)
{
    int i = blockIdx.x * 256 + threadIdx.x;     // N threads
    int s = row_start[i];
    float dg = deg[i];
    int n = cnt_of(dg);
    float a = p1[i];
    int k = 0;
    for (; k + 8 <= n; k += 8) {
        int c0 = adjc[s + k + 0], c1 = adjc[s + k + 1], c2 = adjc[s + k + 2], c3 = adjc[s + k + 3];
        int c4 = adjc[s + k + 4], c5 = adjc[s + k + 5], c6 = adjc[s + k + 6], c7 = adjc[s + k + 7];
        float v0 = p1[c0], v1 = p1[c1], v2 = p1[c2], v3 = p1[c3];
        float v4 = p1[c4], v5 = p1[c5], v6 = p1[c6], v7 = p1[c7];
        a += ((v0 + v1) + (v2 + v3)) + ((v4 + v5) + (v6 + v7));
    }
    for (; k < n; k++) a += p1[adjc[s + k]];
    cat[(long)i * CATLD + 96] = tanhf((a + b[0]) / dg);
}

// ---------------- sortpooling top-K + conv/MLP head (one block per graph) ----------------
__global__ __launch_bounds__(256) void k_topk_head(
    const float* __restrict__ cat,
    const float* __restrict__ Wc1, const float* __restrict__ bc1,
    const float* __restrict__ Wc2, const float* __restrict__ bc2,
    const float* __restrict__ Wh,  const float* __restrict__ bh,
    const float* __restrict__ Wo,  const float* __restrict__ bo,
    float* __restrict__ out)
{
    const int g = blockIdx.x, tid = threadIdx.x;
    __shared__ float vals[NPG_];
    __shared__ int   sel[K_];
    __shared__ float Pm[K_][TLD_];
    __shared__ float redv[4]; __shared__ int redi[4];
    __shared__ float y1[C1_][K_];
    __shared__ float y2[C1_][P2_];
    __shared__ float dd[DENSE_];
    __shared__ float h1s[HID_];
    __shared__ float zz[NCLS_];
    const long gbase = (long)g * NPG_;

    for (int j = tid; j < NPG_; j += 256) vals[j] = cat[(gbase + j) * CATLD + 96];
    __syncthreads();

    // iterative argmax, K times; ties -> lower index (jax.lax.top_k semantics)
    for (int k = 0; k < K_; k++) {
        float bv = -INFINITY; int bi = NPG_;
        for (int j = tid; j < NPG_; j += 256) {
            float v = vals[j];
            if (v > bv) { bv = v; bi = j; }
        }
#pragma unroll
        for (int s = 32; s > 0; s >>= 1) {
            float ov = __shfl_down(bv, s); int oi = __shfl_down(bi, s);
            if (ov > bv || (ov == bv && oi < bi)) { bv = ov; bi = oi; }
        }
        if ((tid & 63) == 0) { redv[tid >> 6] = bv; redi[tid >> 6] = bi; }
        __syncthreads();
        if (tid == 0) {
            for (int w = 1; w < 4; w++)
                if (redv[w] > bv || (redv[w] == bv && redi[w] < bi)) { bv = redv[w]; bi = redi[w]; }
            sel[k] = bi; vals[bi] = -INFINITY;
        }
        __syncthreads();
    }

    for (int t = tid; t < K_ * TLD_; t += 256) {
        int k = t / TLD_, d = t % TLD_;
        Pm[k][d] = cat[(gbase + sel[k]) * CATLD + d];
    }
    __syncthreads();

    for (int t = tid; t < C1_ * K_; t += 256) {
        int c = t / K_, k = t % K_;
        float a = bc1[c];
        for (int d = 0; d < TLD_; d++) a += Pm[k][d] * Wc1[c * TLD_ + d];
        y1[c][k] = fmaxf(a, 0.f);
    }
    __syncthreads();

    for (int t = tid; t < C1_ * P2_; t += 256) {
        int c = t / P2_, u = t % P2_;
        y2[c][u] = fmaxf(y1[c][2 * u], y1[c][2 * u + 1]);
    }
    __syncthreads();

    for (int t = tid; t < C2_ * U_; t += 256) {
        int c2 = t / U_, u = t % U_;
        float a = bc2[c2];
        for (int c = 0; c < C1_; c++)
#pragma unroll
            for (int w = 0; w < KW2_; w++)
                a += y2[c][u + w] * Wc2[(c2 * C1_ + c) * KW2_ + w];
        dd[t] = fmaxf(a, 0.f);
    }
    __syncthreads();

    if (tid < HID_) {
        float a = bh[tid];
        for (int i = 0; i < DENSE_; i++) a += dd[i] * Wh[tid * DENSE_ + i];
        h1s[tid] = fmaxf(a, 0.f);
    }
    __syncthreads();

    if (tid < NCLS_) {
        float a = bo[tid];
        for (int j = 0; j < HID_; j++) a += h1s[j] * Wo[tid * HID_ + j];
        zz[tid] = a;
    }
    __syncthreads();

    if (tid == 0) {
        float m = zz[0];
        for (int c = 1; c < NCLS_; c++) m = fmaxf(m, zz[c]);
        float s = 0.f;
        for (int c = 0; c < NCLS_; c++) s += expf(zz[c] - m);
        float lse = m + logf(s);
        for (int c = 0; c < NCLS_; c++) out[g * NCLS_ + c] = zz[c] - lse;
    }
}

// ---------------- host launch ----------------
extern "C" void kernel_launch(void* const* d_in, const int* in_sizes, int n_in,
                              void* d_out, int out_size, void* d_ws, size_t ws_size,
                              hipStream_t stream)
{
    const float* nf  = (const float*)d_in[0];
    const float* ef  = (const float*)d_in[1];
    const float* deg = (const float*)d_in[2];
    const float* W0  = (const float*)d_in[3];  const float* b0  = (const float*)d_in[4];
    const float* W1  = (const float*)d_in[5];  const float* b1  = (const float*)d_in[6];
    const float* W2  = (const float*)d_in[7];  const float* b2  = (const float*)d_in[8];
    const float* W3  = (const float*)d_in[9];  const float* b3  = (const float*)d_in[10];
    const float* Wc1 = (const float*)d_in[11]; const float* bc1 = (const float*)d_in[12];
    const float* Wc2 = (const float*)d_in[13]; const float* bc2 = (const float*)d_in[14];
    const float* Wh  = (const float*)d_in[15]; const float* bh  = (const float*)d_in[16];
    const float* Wo  = (const float*)d_in[17]; const float* bo  = (const float*)d_in[18];
    const int* erow  = (const int*)d_in[19];
    const int* ecol  = (const int*)d_in[20];
    float* out = (float*)d_out;

    // ---- workspace layout ----
    char* wsb = (char*)d_ws;
    float* e2n       = (float*)wsb;                       wsb += (size_t)N_ * 32 * 4;   // 16 MB
    float* p         = (float*)wsb;                       wsb += (size_t)N_ * 32 * 4;   // 16 MB (also p1)
    float* cat       = (float*)wsb;                       wsb += (size_t)N_ * CATLD * 4;// 64 MB
    int*   row_start = (int*)wsb;                         wsb += (size_t)N_ * 4;
    int*   cursor    = (int*)wsb;                         wsb += (size_t)N_ * 4;
    int*   bsum      = (int*)wsb;                         wsb += 128 * 4;
    int*   adjc      = (int*)wsb;                         wsb += (size_t)E_ * 4;        // 8 MB
    int*   adje      = (int*)wsb;                         /* 8 MB */

    // ---- CSR build (counts derived from node_degs = cnt+1) ----
    k_scan1<<<N_ / 1024, 256, 0, stream>>>(deg, row_start, bsum);
    k_scan2<<<1, 128, 0, stream>>>(bsum);
    k_scan3<<<N_ / 256, 256, 0, stream>>>(row_start, bsum, cursor);
    k_fill<<<E_ / 256, 256, 0, stream>>>(erow, ecol, cursor, adjc, adje);

    // ---- e2n via gather ----
    k_e2n_gather<<<N_ * 32 / 256, 256, 0, stream>>>(ef, row_start, deg, adje, e2n);

    // ---- layer 0 ----
    k_gemm0<<<N_ / 256, 256, 0, stream>>>(nf, e2n, W0, p);
    k_gather_act32<<<N_ * 32 / 256, 256, 0, stream>>>(row_start, adjc, deg, p, b0, cat, 0);
    // ---- layer 1 ----
    k_gemm32<<<N_ / 256, 256, 0, stream>>>(cat, 0, W1, p);
    k_gather_act32<<<N_ * 32 / 256, 256, 0, stream>>>(row_start, adjc, deg, p, b1, cat, 32);
    // ---- layer 2 ----
    k_gemm32<<<N_ / 256, 256, 0, stream>>>(cat, 32, W2, p);
    k_gather_act32<<<N_ * 32 / 256, 256, 0, stream>>>(row_start, adjc, deg, p, b2, cat, 64);
    // ---- layer 3 (D_out = 1, pre-projected) ----
    k_gemm1<<<N_ / 256, 256, 0, stream>>>(cat, 64, W3, p);
    k_gather_act1<<<N_ / 256, 256, 0, stream>>>(row_start, adjc, deg, p, b3, cat);

    // ---- sortpooling + head ----
    k_topk_head<<<B_, 256, 0, stream>>>(cat, Wc1, bc1, Wc2, bc2, Wh, bh, Wo, bo, out);
}

// Round 4
// 448.927 us; speedup vs baseline: 8.1771x; 1.1001x over previous
//
#include <hip/hip_runtime.h>
#include <math.h>

// ---------------- problem constants ----------------
constexpr int B_    = 64;
constexpr int NPG_  = 2048;
constexpr int N_    = B_ * NPG_;        // 131072
constexpr int E_    = N_ * 16;          // 2097152
constexpr int NF_   = 128;
constexpr int EF_   = 32;
constexpr int TLD_  = 97;
constexpr int K_    = 30;
constexpr int C1_   = 16;
constexpr int C2_   = 32;
constexpr int KW2_  = 5;
constexpr int P2_   = 15;
constexpr int U_    = 11;
constexpr int DENSE_= C2_ * U_;         // 352
constexpr int HID_  = 128;
constexpr int NCLS_ = 10;
constexpr int CATLD = 128;              // padded leading dim for cat[N][97]

__device__ __forceinline__ int cnt_of(float d) { return (int)(d + 0.5f) - 1; }

// ---------------- CSR build: scan of (deg-1) ----------------
__global__ __launch_bounds__(256) void k_scan1(const float* __restrict__ deg,
                                               int* __restrict__ part,
                                               int* __restrict__ bsum)
{
    const int t = threadIdx.x;
    const int base = blockIdx.x * 1024 + t * 4;
    int c0 = cnt_of(deg[base + 0]);
    int c1 = cnt_of(deg[base + 1]);
    int c2 = cnt_of(deg[base + 2]);
    int c3 = cnt_of(deg[base + 3]);
    int s = c0 + c1 + c2 + c3;
    int lane = t & 63, w = t >> 6;
    int sc = s;
#pragma unroll
    for (int d = 1; d < 64; d <<= 1) {
        int v = __shfl_up(sc, d);
        if (lane >= d) sc += v;
    }
    __shared__ int wsum[4];
    if (lane == 63) wsum[w] = sc;
    __syncthreads();
    int woff = 0;
    for (int k = 0; k < w; k++) woff += wsum[k];
    int excl = woff + sc - s;
    part[base + 0] = excl;
    part[base + 1] = excl + c0;
    part[base + 2] = excl + c0 + c1;
    part[base + 3] = excl + c0 + c1 + c2;
    if (t == 255) bsum[blockIdx.x] = woff + sc;
}

__global__ __launch_bounds__(128) void k_scan2(int* __restrict__ bsum)
{
    __shared__ int sh[128];
    int t = threadIdx.x;
    sh[t] = bsum[t];
    __syncthreads();
    if (t == 0) {
        int acc = 0;
        for (int i = 0; i < 128; i++) { int v = sh[i]; sh[i] = acc; acc += v; }
    }
    __syncthreads();
    bsum[t] = sh[t];
}

__global__ __launch_bounds__(256) void k_scan3(int* __restrict__ part,
                                               const int* __restrict__ bsum,
                                               int* __restrict__ cursor)
{
    int i = blockIdx.x * 256 + threadIdx.x;
    int v = part[i] + bsum[i >> 10];
    part[i] = v;
    cursor[i] = v;
}

__global__ __launch_bounds__(256) void k_fill(const int* __restrict__ erow,
                                              const int* __restrict__ ecol,
                                              int* __restrict__ cursor,
                                              int* __restrict__ adjc,
                                              int* __restrict__ adje)
{
    int e = blockIdx.x * 256 + threadIdx.x;
    int r = erow[e];
    int slot = atomicAdd(&cursor[r], 1);
    adjc[slot] = ecol[e];
    adje[slot] = e;
}

// ---------------- e2n gather: cooperative index load + shuffle broadcast ----------------
// 32 lanes per row (o = lane&31). Indices for up to 32 edges loaded coalesced by the
// 32 lanes, broadcast via shfl; out-of-range k clamps to last valid index (same
// cacheline -> free) and is masked by weight 0.
__global__ __launch_bounds__(256) void k_e2n_gather(const float* __restrict__ ef,
                                                    const int* __restrict__ row_start,
                                                    const float* __restrict__ deg,
                                                    const int* __restrict__ adje,
                                                    float* __restrict__ e2n)
{
    int gid = blockIdx.x * 256 + threadIdx.x;   // N*32 threads
    int i = gid >> 5, o = gid & 31;
    int s = row_start[i];
    int n = cnt_of(deg[i]);
    float a = 0.f;
    for (int base = 0; base < n; base += 32) {
        int m = n - base; int mi = (m > 32) ? 32 : m;   // >= 1
        int idx = adje[s + base + ((o < mi) ? o : (mi - 1))];
#pragma unroll
        for (int k = 0; k < 32; k++) {
            int e = __shfl(idx, k, 32);
            float w = (k < mi) ? 1.f : 0.f;
            a += w * ef[(long)e * EF_ + o];
        }
    }
    e2n[gid] = a;
}

// ---------------- layer 0 GEMM: p = [nf | e2n] @ W0^T ----------------
__global__ __launch_bounds__(256) void k_gemm0(const float* __restrict__ nf,
                                               const float* __restrict__ e2n,
                                               const float* __restrict__ W0,
                                               float* __restrict__ p)
{
    __shared__ float Ws[32 * 160];
    for (int t = threadIdx.x; t < 32 * 160; t += 256) Ws[t] = W0[t];
    __syncthreads();
    int i = blockIdx.x * 256 + threadIdx.x;
    float acc[32];
#pragma unroll
    for (int o = 0; o < 32; o++) acc[o] = 0.f;
    const float4* row  = reinterpret_cast<const float4*>(nf  + (long)i * NF_);
    const float4* row2 = reinterpret_cast<const float4*>(e2n + (long)i * EF_);
    const float4* Ws4  = reinterpret_cast<const float4*>(Ws);
    for (int d4 = 0; d4 < NF_ / 4; ++d4) {
        float4 v = row[d4];
#pragma unroll
        for (int o = 0; o < 32; o++) {
            float4 w = Ws4[o * 40 + d4];
            acc[o] += v.x * w.x + v.y * w.y + v.z * w.z + v.w * w.w;
        }
    }
#pragma unroll
    for (int d4 = 0; d4 < EF_ / 4; ++d4) {
        float4 v = row2[d4];
#pragma unroll
        for (int o = 0; o < 32; o++) {
            float4 w = Ws4[o * 40 + 32 + d4];
            acc[o] += v.x * w.x + v.y * w.y + v.z * w.z + v.w * w.w;
        }
    }
    float4* p4 = reinterpret_cast<float4*>(p + (long)i * 32);
#pragma unroll
    for (int o4 = 0; o4 < 8; o4++)
        p4[o4] = make_float4(acc[o4*4], acc[o4*4+1], acc[o4*4+2], acc[o4*4+3]);
}

// ---------------- layers 1/2 GEMM: p = cat[:, off:off+32] @ W^T ----------------
__global__ __launch_bounds__(256) void k_gemm32(const float* __restrict__ cat, int in_off,
                                                const float* __restrict__ W,
                                                float* __restrict__ p)
{
    __shared__ float Ws[32 * 32];
    for (int t = threadIdx.x; t < 1024; t += 256) Ws[t] = W[t];
    __syncthreads();
    int i = blockIdx.x * 256 + threadIdx.x;
    float acc[32];
#pragma unroll
    for (int o = 0; o < 32; o++) acc[o] = 0.f;
    const float4* row = reinterpret_cast<const float4*>(cat + (long)i * CATLD + in_off);
    const float4* Ws4 = reinterpret_cast<const float4*>(Ws);
#pragma unroll
    for (int d4 = 0; d4 < 8; ++d4) {
        float4 v = row[d4];
#pragma unroll
        for (int o = 0; o < 32; o++) {
            float4 w = Ws4[o * 8 + d4];
            acc[o] += v.x * w.x + v.y * w.y + v.z * w.z + v.w * w.w;
        }
    }
    float4* p4 = reinterpret_cast<float4*>(p + (long)i * 32);
#pragma unroll
    for (int o4 = 0; o4 < 8; o4++)
        p4[o4] = make_float4(acc[o4*4], acc[o4*4+1], acc[o4*4+2], acc[o4*4+3]);
}

// ---------------- fused gather + activation (32-wide, shuffle-broadcast) ----------------
// Optionally fuses the layer-3 projection (p1 = cat_slice @ W3^T) as a lane reduction.
__global__ __launch_bounds__(256) void k_gather_act32(const int* __restrict__ row_start,
                                                      const int* __restrict__ adjc,
                                                      const float* __restrict__ deg,
                                                      const float* __restrict__ p,
                                                      const float* __restrict__ b,
                                                      float* __restrict__ cat, int out_off,
                                                      const float* __restrict__ W3,
                                                      float* __restrict__ p1)
{
    int gid = blockIdx.x * 256 + threadIdx.x;   // N*32 threads
    int i = gid >> 5, o = gid & 31;
    int s = row_start[i];
    float dg = deg[i];
    int n = cnt_of(dg);
    float a = p[gid];
    for (int base = 0; base < n; base += 32) {
        int m = n - base; int mi = (m > 32) ? 32 : m;
        int idx = adjc[s + base + ((o < mi) ? o : (mi - 1))];
#pragma unroll
        for (int k = 0; k < 32; k++) {
            int c = __shfl(idx, k, 32);
            float w = (k < mi) ? 1.f : 0.f;
            a += w * p[(long)c * 32 + o];
        }
    }
    float t = tanhf((a + b[o]) / dg);
    cat[(long)i * CATLD + out_off + o] = t;
    if (W3 != nullptr) {
        float r = t * W3[o];
#pragma unroll
        for (int sft = 16; sft > 0; sft >>= 1) r += __shfl_xor(r, sft, 32);
        if (o == 0) p1[i] = r;
    }
}

// ---------------- fused gather + activation (1-wide, layer 3, chunk-8 MLP) ----------------
__global__ __launch_bounds__(256) void k_gather_act1(const int* __restrict__ row_start,
                                                     const int* __restrict__ adjc,
                                                     const float* __restrict__ deg,
                                                     const float* __restrict__ p1,
                                                     const float* __restrict__ b,
                                                     float* __restrict__ cat)
{
    int i = blockIdx.x * 256 + threadIdx.x;     // N threads
    int s = row_start[i];
    float dg = deg[i];
    int n = cnt_of(dg);
    float a = p1[i];
    int k = 0;
    for (; k + 8 <= n; k += 8) {
        int c0 = adjc[s + k + 0], c1 = adjc[s + k + 1], c2 = adjc[s + k + 2], c3 = adjc[s + k + 3];
        int c4 = adjc[s + k + 4], c5 = adjc[s + k + 5], c6 = adjc[s + k + 6], c7 = adjc[s + k + 7];
        float v0 = p1[c0], v1 = p1[c1], v2 = p1[c2], v3 = p1[c3];
        float v4 = p1[c4], v5 = p1[c5], v6 = p1[c6], v7 = p1[c7];
        a += ((v0 + v1) + (v2 + v3)) + ((v4 + v5) + (v6 + v7));
    }
    for (; k < n; k++) a += p1[adjc[s + k]];
    cat[(long)i * CATLD + 96] = tanhf((a + b[0]) / dg);
}

// ---------------- sortpooling top-K + conv/MLP head (one block per graph) ----------------
__global__ __launch_bounds__(256) void k_topk_head(
    const float* __restrict__ cat,
    const float* __restrict__ Wc1, const float* __restrict__ bc1,
    const float* __restrict__ Wc2, const float* __restrict__ bc2,
    const float* __restrict__ Wh,  const float* __restrict__ bh,
    const float* __restrict__ Wo,  const float* __restrict__ bo,
    float* __restrict__ out)
{
    const int g = blockIdx.x, tid = threadIdx.x;
    __shared__ float vals[NPG_];
    __shared__ int   sel[K_];
    __shared__ float Pm[K_][TLD_];
    __shared__ float redv[4]; __shared__ int redi[4];
    __shared__ float y1[C1_][K_];
    __shared__ float y2[C1_][P2_];
    __shared__ float dd[DENSE_];
    __shared__ float h1s[HID_];
    __shared__ float zz[NCLS_];
    const long gbase = (long)g * NPG_;

    for (int j = tid; j < NPG_; j += 256) vals[j] = cat[(gbase + j) * CATLD + 96];
    __syncthreads();

    // iterative argmax, K times; ties -> lower index (jax.lax.top_k semantics)
    for (int k = 0; k < K_; k++) {
        float bv = -INFINITY; int bi = NPG_;
        for (int j = tid; j < NPG_; j += 256) {
            float v = vals[j];
            if (v > bv) { bv = v; bi = j; }
        }
#pragma unroll
        for (int s = 32; s > 0; s >>= 1) {
            float ov = __shfl_down(bv, s); int oi = __shfl_down(bi, s);
            if (ov > bv || (ov == bv && oi < bi)) { bv = ov; bi = oi; }
        }
        if ((tid & 63) == 0) { redv[tid >> 6] = bv; redi[tid >> 6] = bi; }
        __syncthreads();
        if (tid == 0) {
            for (int w = 1; w < 4; w++)
                if (redv[w] > bv || (redv[w] == bv && redi[w] < bi)) { bv = redv[w]; bi = redi[w]; }
            sel[k] = bi; vals[bi] = -INFINITY;
        }
        __syncthreads();
    }

    for (int t = tid; t < K_ * TLD_; t += 256) {
        int k = t / TLD_, d = t % TLD_;
        Pm[k][d] = cat[(gbase + sel[k]) * CATLD + d];
    }
    __syncthreads();

    for (int t = tid; t < C1_ * K_; t += 256) {
        int c = t / K_, k = t % K_;
        float a = bc1[c];
        for (int d = 0; d < TLD_; d++) a += Pm[k][d] * Wc1[c * TLD_ + d];
        y1[c][k] = fmaxf(a, 0.f);
    }
    __syncthreads();

    for (int t = tid; t < C1_ * P2_; t += 256) {
        int c = t / P2_, u = t % P2_;
        y2[c][u] = fmaxf(y1[c][2 * u], y1[c][2 * u + 1]);
    }
    __syncthreads();

    for (int t = tid; t < C2_ * U_; t += 256) {
        int c2 = t / U_, u = t % U_;
        float a = bc2[c2];
        for (int c = 0; c < C1_; c++)
#pragma unroll
            for (int w = 0; w < KW2_; w++)
                a += y2[c][u + w] * Wc2[(c2 * C1_ + c) * KW2_ + w];
        dd[t] = fmaxf(a, 0.f);
    }
    __syncthreads();

    if (tid < HID_) {
        float a = bh[tid];
        for (int i = 0; i < DENSE_; i++) a += dd[i] * Wh[tid * DENSE_ + i];
        h1s[tid] = fmaxf(a, 0.f);
    }
    __syncthreads();

    if (tid < NCLS_) {
        float a = bo[tid];
        for (int j = 0; j < HID_; j++) a += h1s[j] * Wo[tid * HID_ + j];
        zz[tid] = a;
    }
    __syncthreads();

    if (tid == 0) {
        float m = zz[0];
        for (int c = 1; c < NCLS_; c++) m = fmaxf(m, zz[c]);
        float s = 0.f;
        for (int c = 0; c < NCLS_; c++) s += expf(zz[c] - m);
        float lse = m + logf(s);
        for (int c = 0; c < NCLS_; c++) out[g * NCLS_ + c] = zz[c] - lse;
    }
}

// ---------------- host launch ----------------
extern "C" void kernel_launch(void* const* d_in, const int* in_sizes, int n_in,
                              void* d_out, int out_size, void* d_ws, size_t ws_size,
                              hipStream_t stream)
{
    const float* nf  = (const float*)d_in[0];
    const float* ef  = (const float*)d_in[1];
    const float* deg = (const float*)d_in[2];
    const float* W0  = (const float*)d_in[3];  const float* b0  = (const float*)d_in[4];
    const float* W1  = (const float*)d_in[5];  const float* b1  = (const float*)d_in[6];
    const float* W2  = (const float*)d_in[7];  const float* b2  = (const float*)d_in[8];
    const float* W3  = (const float*)d_in[9];  const float* b3  = (const float*)d_in[10];
    const float* Wc1 = (const float*)d_in[11]; const float* bc1 = (const float*)d_in[12];
    const float* Wc2 = (const float*)d_in[13]; const float* bc2 = (const float*)d_in[14];
    const float* Wh  = (const float*)d_in[15]; const float* bh  = (const float*)d_in[16];
    const float* Wo  = (const float*)d_in[17]; const float* bo  = (const float*)d_in[18];
    const int* erow  = (const int*)d_in[19];
    const int* ecol  = (const int*)d_in[20];
    float* out = (float*)d_out;

    // ---- workspace layout ----
    char* wsb = (char*)d_ws;
    float* e2n       = (float*)wsb;                       wsb += (size_t)N_ * 32 * 4;   // 16 MB
    float* p         = (float*)wsb;                       wsb += (size_t)N_ * 32 * 4;   // 16 MB
    float* cat       = (float*)wsb;                       wsb += (size_t)N_ * CATLD * 4;// 64 MB
    float* p1        = (float*)wsb;                       wsb += (size_t)N_ * 4;        // 0.5 MB
    int*   row_start = (int*)wsb;                         wsb += (size_t)N_ * 4;
    int*   cursor    = (int*)wsb;                         wsb += (size_t)N_ * 4;
    int*   bsum      = (int*)wsb;                         wsb += 128 * 4;
    int*   adjc      = (int*)wsb;                         wsb += (size_t)E_ * 4;        // 8 MB
    int*   adje      = (int*)wsb;                         /* 8 MB */

    // ---- CSR build (counts derived from node_degs = cnt+1) ----
    k_scan1<<<N_ / 1024, 256, 0, stream>>>(deg, row_start, bsum);
    k_scan2<<<1, 128, 0, stream>>>(bsum);
    k_scan3<<<N_ / 256, 256, 0, stream>>>(row_start, bsum, cursor);
    k_fill<<<E_ / 256, 256, 0, stream>>>(erow, ecol, cursor, adjc, adje);

    // ---- e2n via gather ----
    k_e2n_gather<<<N_ * 32 / 256, 256, 0, stream>>>(ef, row_start, deg, adje, e2n);

    // ---- layer 0 ----
    k_gemm0<<<N_ / 256, 256, 0, stream>>>(nf, e2n, W0, p);
    k_gather_act32<<<N_ * 32 / 256, 256, 0, stream>>>(row_start, adjc, deg, p, b0, cat, 0, nullptr, nullptr);
    // ---- layer 1 ----
    k_gemm32<<<N_ / 256, 256, 0, stream>>>(cat, 0, W1, p);
    k_gather_act32<<<N_ * 32 / 256, 256, 0, stream>>>(row_start, adjc, deg, p, b1, cat, 32, nullptr, nullptr);
    // ---- layer 2 (+ fused layer-3 projection into p1) ----
    k_gemm32<<<N_ / 256, 256, 0, stream>>>(cat, 32, W2, p);
    k_gather_act32<<<N_ * 32 / 256, 256, 0, stream>>>(row_start, adjc, deg, p, b2, cat, 64, W3, p1);
    // ---- layer 3 (D_out = 1, pre-projected) ----
    k_gather_act1<<<N_ / 256, 256, 0, stream>>>(row_start, adjc, deg, p1, b3, cat);

    // ---- sortpooling + head ----
    k_topk_head<<<B_, 256, 0, stream>>>(cat, Wc1, bc1, Wc2, bc2, Wh, bh, Wo, bo, out);
}